// Round 3
// baseline (693.341 us; speedup 1.0000x reference)
//
#include <hip/hip_runtime.h>
#include <math.h>

#define NQ 12
#define DIM 4096
#define NL 6
#define TPB 64   // one wave per block = one batch element; no cross-wave sync

// ---------------------------------------------------------------------------
// State storage: LOGICAL basis — slot s holds amplitude of basis label s.
// Each layer = 12 Rot gates (wires 0..11) + CNOT block. The CNOT block is a
// GF(2)-linear label permutation: new label = gray(old) = old ^ (old>>1)
// (validated in R1/R2). We fold it into the store addresses of pass 2, so
// gates ALWAYS pair v[j] <-> v[j ^ (1<<bit)] with raw gate coefficients —
// no parity masks, no coefficient selects.
//
// Pass 1: lane L owns labels [L*64, L*64+64)  -> gates on label bits 0..5
//         (wires 11..6), contiguous b128 LDS I/O.
// Pass 2: lane L owns labels {L + c*64}       -> gates on label bits 6..11
//         (wires 5..0), strided b64 LDS I/O.
//
// Bank swizzle (linear over GF(2)): key(s) = (s>>9)&7,
//   phys_byte(s) = (((s>>1) ^ key) << 4) | ((s&1) << 3)
// Linearity lets every access reduce to base_reg[static] + immediate, or
// base ^ compile-time literal for the gray-folded stores.
// ---------------------------------------------------------------------------

// gray-fold store address, c-part (compile-time): label = L + (c<<6),
// sigma = gray(label) = g6(L) ^ W(c), W(c) = (c<<6)^(c<<5).
constexpr int qc_calc(int c) {
  int W = ((c << 6) ^ (c << 5)) & 0xFFF;
  int key = ((c >> 3) ^ (c >> 4)) & 7;
  return ((W >> 1) ^ key) << 4;          // byte offset part (bit 3 untouched)
}
#define QC8(b) qc_calc(b), qc_calc(b+1), qc_calc(b+2), qc_calc(b+3), \
               qc_calc(b+4), qc_calc(b+5), qc_calc(b+6), qc_calc(b+7)
__device__ constexpr int QC[64] = { QC8(0), QC8(8), QC8(16), QC8(24),
                                    QC8(32), QC8(40), QC8(48), QC8(56) };

// Apply 2x2 complex gate to all 32 pairs (j, j^(1<<BIT)) of v[64].
// cA = (g00.re, g00.im, g01.re, g01.im), cB = (g10.., g11..)
template<int BIT>
__device__ __forceinline__ void apply_gate(float2 v[64], float4 cA, float4 cB) {
  #pragma unroll
  for (int j = 0; j < 64; ++j) {
    if (j & (1 << BIT)) continue;
    const int k = j | (1 << BIT);
    float2 a = v[j], b = v[k];
    float nax = cA.x*a.x - cA.y*a.y + cA.z*b.x - cA.w*b.y;
    float nay = cA.x*a.y + cA.y*a.x + cA.z*b.y + cA.w*b.x;
    float nbx = cB.x*a.x - cB.y*a.y + cB.z*b.x - cB.w*b.y;
    float nby = cB.x*a.y + cB.y*a.x + cB.z*b.y + cB.w*b.x;
    v[j] = make_float2(nax, nay);
    v[k] = make_float2(nbx, nby);
  }
}

__global__ __launch_bounds__(TPB, 1)
void qsim12_kernel(const float* __restrict__ x, const float* __restrict__ w,
                   float* __restrict__ out) {
  __shared__ __align__(16) float st[2*DIM];     // 32 KB state (swizzled layout)
  __shared__ float4 gmq[NL*NQ*2];               // Rot matrices, 2 float4/gate
  __shared__ float2 cs[NQ];                     // cos/sin(x_q/2)

  const int L = threadIdx.x;                    // lane (block = 1 wave)
  const int b = blockIdx.x;

  // Rot(phi,theta,omega) = RZ(om) RY(th) RZ(phi):
  //   m00 = ct e^{-i(phi+om)/2}, m01 = -st e^{+i(phi-om)/2}
  //   m10 = st e^{-i(phi-om)/2}, m11 = ct e^{+i(phi+om)/2}
  for (int gi = L; gi < NL*NQ; gi += TPB) {
    const float* wp = w + gi*3;
    float phi = wp[0], th = wp[1], om = wp[2];
    float sth, cth; sincosf(0.5f*th, &sth, &cth);
    float sa, ca;   sincosf(0.5f*(phi+om), &sa, &ca);
    float sb, cb;   sincosf(0.5f*(phi-om), &sb, &cb);
    gmq[gi*2+0] = make_float4( cth*ca, -cth*sa, -sth*cb, -sth*sb);  // g00,g01
    gmq[gi*2+1] = make_float4( sth*cb, -sth*sb,  cth*ca,  cth*sa);  // g10,g11
  }
  for (int q = L; q < NQ; q += TPB) {
    float xv = x[b*NQ + q];
    float sv, cv; sincosf(0.5f*xv, &sv, &cv);
    cs[q] = make_float2(cv, sv);
  }
  __syncthreads();

  // Precomputed LDS address bases (all per-access indices become static).
  char* stb = (char*)st;
  const int key1 = (L >> 3) & 7;
  int base1[8], baseB[8];
  #pragma unroll
  for (int t = 0; t < 8; ++t) {
    base1[t] = (L << 9) + ((t ^ key1) << 4);              // pass-1 b128 bases
    baseB[t] = (((L >> 1) ^ t) << 4) + ((L & 1) << 3);    // pass-2 b64 bases
  }
  const int g6 = L ^ (L >> 1);                            // gray(L), < 64
  const int Pbase8 = ((g6 >> 1) << 4) + ((g6 & 1) << 3);  // gray-fold lane part

  float2 v[64];

  // ---- Init: |0..0> through RX(x_q) is a tensor product:
  // amp(label) = prod_w (bit_w ? sin_w : cos_w) * (-i)^popcount(label).
  // Lane L's pass-1 chunk: labels L*64+j. Label bit (6+k) = L bit k = wire 5-k;
  // label bit m (m<6) = j bit m = wire 11-m.
  {
    float2 csr[NQ];
    #pragma unroll
    for (int q = 0; q < NQ; ++q) csr[q] = cs[q];
    float rhi = 1.f;
    #pragma unroll
    for (int k = 0; k < 6; ++k)
      rhi *= ((L >> k) & 1) ? csr[5-k].y : csr[5-k].x;
    const int p = __popc(L) & 3;                 // (-i)^p per-lane phase
    const float phx = (p == 0) ? 1.f : ((p == 2) ? -1.f : 0.f);
    const float phy = (p == 1) ? -1.f : ((p == 3) ? 1.f : 0.f);
    #pragma unroll
    for (int j = 0; j < 64; ++j) {
      float r = rhi;
      #pragma unroll
      for (int m = 0; m < 6; ++m)
        r *= ((j >> m) & 1) ? csr[11-m].y : csr[11-m].x;   // static operand pick
      const int pj = __popc(j) & 3;                        // static rotation
      float2 amp;
      if      (pj == 0) amp = make_float2( r*phx,  r*phy);
      else if (pj == 1) amp = make_float2( r*phy, -r*phx);
      else if (pj == 2) amp = make_float2(-r*phx, -r*phy);
      else              amp = make_float2(-r*phy,  r*phx);
      v[j] = amp;
    }
  }

  #pragma unroll 1
  for (int l = 0; l < NL; ++l) {
    // ---- pass 1: wires 11..6 (label bits 0..5), v[] holds chunk by raw j
    if (l > 0) {
      #pragma unroll
      for (int m = 0; m < 32; ++m) {
        float4 t = *(const float4*)(stb + base1[m & 7] + ((m & ~7) << 4));
        v[2*m]   = make_float2(t.x, t.y);
        v[2*m+1] = make_float2(t.z, t.w);
      }
    }
    #pragma unroll
    for (int bit = 0; bit < 6; ++bit) {
      const int wq = 11 - bit;
      float4 cA = gmq[(l*NQ + wq)*2 + 0];
      float4 cB = gmq[(l*NQ + wq)*2 + 1];
      switch (bit) {  // static dispatch (bit is compile-time under unroll)
        case 0: apply_gate<0>(v, cA, cB); break;
        case 1: apply_gate<1>(v, cA, cB); break;
        case 2: apply_gate<2>(v, cA, cB); break;
        case 3: apply_gate<3>(v, cA, cB); break;
        case 4: apply_gate<4>(v, cA, cB); break;
        case 5: apply_gate<5>(v, cA, cB); break;
      }
    }
    #pragma unroll
    for (int m = 0; m < 32; ++m) {
      float4 t = make_float4(v[2*m].x, v[2*m].y, v[2*m+1].x, v[2*m+1].y);
      *(float4*)(stb + base1[m & 7] + ((m & ~7) << 4)) = t;
    }
    __syncthreads();

    // ---- pass 2: wires 5..0 (label bits 6..11); v[c] = label L + c*64
    #pragma unroll
    for (int c = 0; c < 64; ++c)
      v[c] = *(const float2*)(stb + baseB[(c >> 3) & 7] + c*512);
    #pragma unroll
    for (int ci = 0; ci < 6; ++ci) {
      const int wq = 5 - ci;
      float4 cA = gmq[(l*NQ + wq)*2 + 0];
      float4 cB = gmq[(l*NQ + wq)*2 + 1];
      switch (ci) {
        case 0: apply_gate<0>(v, cA, cB); break;
        case 1: apply_gate<1>(v, cA, cB); break;
        case 2: apply_gate<2>(v, cA, cB); break;
        case 3: apply_gate<3>(v, cA, cB); break;
        case 4: apply_gate<4>(v, cA, cB); break;
        case 5: apply_gate<5>(v, cA, cB); break;
      }
    }
    if (l < NL-1) {
      // store with CNOT-block fold: slot = gray(label) = g6(L) ^ W(c)
      #pragma unroll
      for (int c = 0; c < 64; ++c)
        *(float2*)(stb + (Pbase8 ^ QC[c])) = v[c];
      __syncthreads();
    }
  }

  // ---- Epilogue: final labels are gray(L + c*64); measured wires 0,1 =
  // label bits 11,10 of gray = (c5, c4^c5) -> static signs. Wave-reduce.
  float a0 = 0.f, a1 = 0.f;
  #pragma unroll
  for (int c = 0; c < 64; ++c) {
    float pr = v[c].x*v[c].x + v[c].y*v[c].y;
    a0 += ((c >> 5) & 1) ? -pr : pr;
    a1 += (((c >> 4) ^ (c >> 5)) & 1) ? -pr : pr;
  }
  #pragma unroll
  for (int off = 32; off >= 1; off >>= 1) {
    a0 += __shfl_down(a0, off);
    a1 += __shfl_down(a1, off);
  }
  if (L == 0) {
    out[b*2 + 0] = a0;
    out[b*2 + 1] = a1;
  }
}

extern "C" void kernel_launch(void* const* d_in, const int* in_sizes, int n_in,
                              void* d_out, int out_size, void* d_ws, size_t ws_size,
                              hipStream_t stream) {
  const float* x = (const float*)d_in[0];      // (B, 12) f32
  const float* w = (const float*)d_in[1];      // (6, 12, 3) f32
  float* out = (float*)d_out;                  // (B, 2) f32
  int B = in_sizes[0] / NQ;
  qsim12_kernel<<<B, TPB, 0, stream>>>(x, w, out);
}

// Round 5
// 232.893 us; speedup vs baseline: 2.9771x; 2.9771x over previous
//
#include <hip/hip_runtime.h>
#include <math.h>

#define NQ 12
#define DIM 4096
#define NL 6
#define TPB 256

// ---------------------------------------------------------------------------
// State in the LOGICAL basis; the per-layer CNOT block (label -> gray(label),
// validated R1-R3) is folded into pass-C's store addresses. Gates therefore
// always pair v[j] <-> v[j^(1<<bit)] with raw Rot coefficients — no parity
// masks, no coefficient selects.
//
// 256 threads x 16 amps, 3 passes/layer:
//   pass A: thread t owns labels t*16+j     -> gates on label bits 0..3  (wires 11..8)
//   pass B: owns (t&15) | j<<4 | (t>>4)<<8  -> gates on label bits 4..7  (wires 7..4)
//   pass C: owns t | j<<8                   -> gates on label bits 8..11 (wires 3..0)
//
// Swizzled layouts (GF(2)-linear, so every access = base reg + immediate,
// occasionally one v_xor):
//   A-store/A-load & B-load layout: phys14(s) = s ^ ((s>>4)&14)  (even key
//     preserves b128 pairs; B-load conflict-free, A b128 2-way = free)
//   B-store & C-load layout:        phys15(s) = s ^ ((s>>4)&15)  (conflict-free
//     both sides)
//   C-store: slot sigma = gray(s) = s^(s>>1) in layout phys14. For s = t|j<<8:
//     sigma = [G ^ (j0<<7)] | (gray4(j)<<8),  G = t^(t>>1), gray4(j)=j^(j>>1).
//     (R4 bug: used j, not gray4(j), for the high nibble. Fixed; verified
//      numerically against 8*phys14(gray(s)) for multiple (t,j).)
// ---------------------------------------------------------------------------

// 2x2 complex gate on the 8 pairs (j, j^(1<<BIT)) of v[16].
// cA = (g00.re, g00.im, g01.re, g01.im), cB = (g10.., g11..)
template<int BIT>
__device__ __forceinline__ void apply_gate16(float2 v[16], float4 cA, float4 cB) {
  #pragma unroll
  for (int j = 0; j < 16; ++j) {
    if (j & (1 << BIT)) continue;
    const int k = j | (1 << BIT);
    float2 a = v[j], b = v[k];
    float nax = cA.x*a.x - cA.y*a.y + cA.z*b.x - cA.w*b.y;
    float nay = cA.x*a.y + cA.y*a.x + cA.z*b.y + cA.w*b.x;
    float nbx = cB.x*a.x - cB.y*a.y + cB.z*b.x - cB.w*b.y;
    float nby = cB.x*a.y + cB.y*a.x + cB.z*b.y + cB.w*b.x;
    v[j] = make_float2(nax, nay);
    v[k] = make_float2(nbx, nby);
  }
}

__global__ __launch_bounds__(TPB, 4)
void qsim12_kernel(const float* __restrict__ x, const float* __restrict__ w,
                   float* __restrict__ out) {
  __shared__ __align__(16) float st[2*DIM];     // 32 KB state (swizzled)
  __shared__ float4 gmq[NL*NQ*2];               // Rot matrices
  __shared__ float2 cs[NQ];                     // cos/sin(x_q/2)
  __shared__ float red[8];

  const int t = threadIdx.x;
  const int b = blockIdx.x;

  // Rot(phi,theta,omega) = RZ(om) RY(th) RZ(phi):
  //   m00 = ct e^{-i(phi+om)/2}, m01 = -st e^{+i(phi-om)/2}
  //   m10 = st e^{-i(phi-om)/2}, m11 = ct e^{+i(phi+om)/2}
  if (t < NL*NQ) {
    const float* wp = w + t*3;
    float phi = wp[0], th = wp[1], om = wp[2];
    float sth, cth; sincosf(0.5f*th, &sth, &cth);
    float sa, ca;   sincosf(0.5f*(phi+om), &sa, &ca);
    float sb, cb;   sincosf(0.5f*(phi-om), &sb, &cb);
    gmq[t*2+0] = make_float4( cth*ca, -cth*sa, -sth*cb, -sth*sb);  // g00,g01
    gmq[t*2+1] = make_float4( sth*cb, -sth*sb,  cth*ca,  cth*sa);  // g10,g11
  }
  if (t >= 128 && t < 128 + NQ) {
    int q = t - 128;
    float xv = x[b*NQ + q];
    float sv, cv; sincosf(0.5f*xv, &sv, &cv);
    cs[q] = make_float2(cv, sv);
  }
  __syncthreads();

  char* stb = (char*)st;

  // Precomputed byte-address bases (per-access index static after unroll).
  int baseA[8], baseB[8];
  #pragma unroll
  for (int m = 0; m < 8; ++m) {
    baseA[m] = (t << 7) + (((2*m) ^ (t & 14)) << 3);                 // phys14, A b128
    baseB[m] = ((t >> 4) << 11) + ((((t & 15) ^ (2*m))) << 3);       // + j*128
  }
  const int baseC = ((t >> 4) << 7) + ((((t & 15) ^ ((t >> 4) & 15))) << 3);  // + j*2048
  const int G = t ^ (t >> 1);                                        // gray(t), 8 bits
  // C-store bases: sigma bits 4..7 = (G>>4) ^ (j0<<3); swizzle key =
  // (sigma>>4)&14 = ((G>>4)&14) ^ (j0<<3); low nibble = (G&15) ^ key.
  // High nibble gray4(j) added per-j at the store site.
  int baseS[2];
  #pragma unroll
  for (int par = 0; par < 2; ++par) {
    const int k8 = par << 3;
    baseS[par] = ((((G >> 4) & 15) ^ k8) << 7)
               + ((((G & 15) ^ ((G >> 4) & 14) ^ k8)) << 3);
  }

  float2 v[16];

  // ---- Init: |0..0> through RX(x_q): amp(label) = prod_w (bit? sin:cos) *
  // (-i)^popcount. Pass-A ownership: label = t*16+j; label bit 4+k = t bit k
  // (wire 7-k), label bit m (m<4) = j bit m (wire 11-m).
  {
    float2 csr[NQ];
    #pragma unroll
    for (int q = 0; q < NQ; ++q) csr[q] = cs[q];
    float rhi = 1.f;
    #pragma unroll
    for (int k = 0; k < 8; ++k)
      rhi *= ((t >> k) & 1) ? csr[7-k].y : csr[7-k].x;
    const int popt = __popc(t);
    #pragma unroll
    for (int j = 0; j < 16; ++j) {
      float r = rhi;
      #pragma unroll
      for (int m = 0; m < 4; ++m)
        r *= ((j >> m) & 1) ? csr[11-m].y : csr[11-m].x;
      const int pj = (popt + __popc(j)) & 3;     // static select per j
      float2 amp;
      if      (pj == 0) amp = make_float2( r, 0.f);
      else if (pj == 1) amp = make_float2(0.f, -r);
      else if (pj == 2) amp = make_float2(-r, 0.f);
      else              amp = make_float2(0.f,  r);
      v[j] = amp;
    }
  }

  #define GATE(BIT, WQ)                                        \
    { float4 cA = gmq[(l*NQ + (WQ))*2 + 0];                    \
      float4 cB = gmq[(l*NQ + (WQ))*2 + 1];                    \
      apply_gate16<BIT>(v, cA, cB); }

  #pragma unroll 1
  for (int l = 0; l < NL; ++l) {
    // ---- pass A: wires 11..8 (label bits 0..3)
    if (l > 0) {
      #pragma unroll
      for (int m = 0; m < 8; ++m) {
        float4 q4 = *(const float4*)(stb + baseA[m]);
        v[2*m]   = make_float2(q4.x, q4.y);
        v[2*m+1] = make_float2(q4.z, q4.w);
      }
    }
    GATE(0,11) GATE(1,10) GATE(2,9) GATE(3,8)
    #pragma unroll
    for (int m = 0; m < 8; ++m)
      *(float4*)(stb + baseA[m]) =
          make_float4(v[2*m].x, v[2*m].y, v[2*m+1].x, v[2*m+1].y);
    __syncthreads();

    // ---- pass B: wires 7..4 (label bits 4..7); load layout phys14
    #pragma unroll
    for (int m = 0; m < 8; ++m) {
      v[2*m]   = *(const float2*)(stb + baseB[m] + (2*m)*128);
      v[2*m+1] = *(const float2*)(stb + baseB[m] + (2*m+1)*128);
    }
    GATE(0,7) GATE(1,6) GATE(2,5) GATE(3,4)
    // store layout phys15: odd j flips bit 3 of the swizzled low nibble
    #pragma unroll
    for (int m = 0; m < 8; ++m) {
      *(float2*)(stb + baseB[m] + (2*m)*128)         = v[2*m];
      *(float2*)(stb + (baseB[m] ^ 8) + (2*m+1)*128) = v[2*m+1];
    }
    __syncthreads();

    // ---- pass C: wires 3..0 (label bits 8..11); load layout phys15
    #pragma unroll
    for (int j = 0; j < 16; ++j)
      v[j] = *(const float2*)(stb + baseC + j*2048);
    GATE(0,3) GATE(1,2) GATE(2,1) GATE(3,0)
    if (l < NL-1) {
      // store with CNOT-block fold: slot = gray(label), layout phys14;
      // high nibble of gray(label) = gray4(j) (compile-time per j)
      #pragma unroll
      for (int j = 0; j < 16; ++j) {
        const int g4 = (j ^ (j >> 1)) & 15;
        *(float2*)(stb + baseS[j & 1] + (g4 << 11)) = v[j];
      }
      __syncthreads();
    }
  }

  // ---- Epilogue: labels s = t | j<<8; final (post-CNOT) label = gray(s):
  // wire0 = bit11 = s11 = j3; wire1 = bit10 = s10^s11 = j2^j3. Static signs.
  float a0 = 0.f, a1 = 0.f;
  #pragma unroll
  for (int j = 0; j < 16; ++j) {
    float pr = v[j].x*v[j].x + v[j].y*v[j].y;
    a0 += ((j >> 3) & 1) ? -pr : pr;
    a1 += (((j >> 2) ^ (j >> 3)) & 1) ? -pr : pr;
  }
  #pragma unroll
  for (int off = 32; off >= 1; off >>= 1) {
    a0 += __shfl_down(a0, off);
    a1 += __shfl_down(a1, off);
  }
  if ((t & 63) == 0) { red[(t >> 6)*2] = a0; red[(t >> 6)*2 + 1] = a1; }
  __syncthreads();
  if (t == 0) {
    out[b*2 + 0] = red[0] + red[2] + red[4] + red[6];
    out[b*2 + 1] = red[1] + red[3] + red[5] + red[7];
  }
}

extern "C" void kernel_launch(void* const* d_in, const int* in_sizes, int n_in,
                              void* d_out, int out_size, void* d_ws, size_t ws_size,
                              hipStream_t stream) {
  const float* x = (const float*)d_in[0];      // (B, 12) f32
  const float* w = (const float*)d_in[1];      // (6, 12, 3) f32
  float* out = (float*)d_out;                  // (B, 2) f32
  int B = in_sizes[0] / NQ;
  qsim12_kernel<<<B, TPB, 0, stream>>>(x, w, out);
}

// Round 7
// 158.684 us; speedup vs baseline: 4.3693x; 1.4676x over previous
//
#include <hip/hip_runtime.h>
#include <math.h>

#define NQ 12
#define DIM 4096
#define NL 6
#define TPB 256

typedef float f2 __attribute__((ext_vector_type(2)));

// ---------------------------------------------------------------------------
// Single kernel (R6's two-kernel d_ws handoff broke graph-replay coherence —
// launch_once vs replay diverged; everything stays in-block now).
//
// Structure (verified R5): state in LOGICAL basis, CNOT block = label ->
// gray(label) folded into pass-C store addresses; 3 passes/layer over label
// bits 0-3 / 4-7 / 8-11; GF(2)-linear bank swizzles:
//   A-layout (A I/O, B-load): phys14(s) = s ^ ((s>>4)&14)
//   B-store / C-load:         phys15(s) = s ^ ((s>>4)&15)
//   C-store: sigma = gray(s), layout phys14; high nibble = gray4(j).
// Gate math (verified R6 launch_once): v_pk_fma_f32, 8 packed ops per
// complex 2x2 pair update. Coefficients precomputed by threads 0..71 into
// LDS, duplicated per half: [g00r,g00r,g00i,g00i, g01..,g10..,g11..].
// ---------------------------------------------------------------------------

__device__ __forceinline__ f2 pk_mul(f2 a, f2 b) {
  f2 d; asm("v_pk_mul_f32 %0, %1, %2" : "=v"(d) : "v"(a), "v"(b)); return d;
}
__device__ __forceinline__ f2 pk_fma(f2 a, f2 b, f2 c) {
  f2 d; asm("v_pk_fma_f32 %0, %1, %2, %3" : "=v"(d) : "v"(a), "v"(b), "v"(c)); return d;
}
// d = (-a.y*b.x + c.x, a.x*b.y + c.y)  (swap halves of a, negate new lo)
__device__ __forceinline__ f2 pk_fma_sn(f2 a, f2 b, f2 c) {
  f2 d; asm("v_pk_fma_f32 %0, %1, %2, %3 op_sel:[1,0,0] op_sel_hi:[0,1,1] neg_lo:[1,0,0]"
            : "=v"(d) : "v"(a), "v"(b), "v"(c)); return d;
}

// a' = c0*a + c1*b ; b' = c2*a + c3*b  (complex), coefficients (re,re)/(im,im)
template<int BIT>
__device__ __forceinline__ void apply_gate16(f2 v[16],
    f2 c0r, f2 c0i, f2 c1r, f2 c1i, f2 c2r, f2 c2i, f2 c3r, f2 c3i) {
  #pragma unroll
  for (int j = 0; j < 16; ++j) {
    if (j & (1 << BIT)) continue;
    const int k = j | (1 << BIT);
    f2 a = v[j], b = v[k];
    f2 na = pk_fma_sn(b, c1i, pk_fma(b, c1r, pk_fma_sn(a, c0i, pk_mul(a, c0r))));
    f2 nb = pk_fma_sn(b, c3i, pk_fma(b, c3r, pk_fma_sn(a, c2i, pk_mul(a, c2r))));
    v[j] = na; v[k] = nb;
  }
}

__global__ __launch_bounds__(TPB, 4)
void qsim12_kernel(const float* __restrict__ x, const float* __restrict__ w,
                   float* __restrict__ out) {
  __shared__ __align__(16) float st[2*DIM];       // 32 KB state (swizzled)
  __shared__ __align__(16) float gmp[NL*NQ*16];   // packed gates, 4.6 KB
  __shared__ float2 cs[NQ];                       // cos/sin(x_q/2)

  const int t = threadIdx.x;
  const int b = blockIdx.x;
  char* stb = (char*)st;

  // Rot(phi,theta,omega) = RZ(om) RY(th) RZ(phi):
  //   g00 = ct e^{-i(phi+om)/2}, g01 = -st e^{+i(phi-om)/2}
  //   g10 = st e^{-i(phi-om)/2}, g11 = ct e^{+i(phi+om)/2}
  if (t < NL*NQ) {
    const float* wp = w + t*3;
    float phi = wp[0], th = wp[1], om = wp[2];
    float sth, cth; sincosf(0.5f*th, &sth, &cth);
    float sa, ca;   sincosf(0.5f*(phi+om), &sa, &ca);
    float sb, cb;   sincosf(0.5f*(phi-om), &sb, &cb);
    float* o = gmp + t*16;
    o[0]=o[1]=cth*ca;   o[2]=o[3]=-cth*sa;    // g00
    o[4]=o[5]=-sth*cb;  o[6]=o[7]=-sth*sb;    // g01
    o[8]=o[9]=sth*cb;   o[10]=o[11]=-sth*sb;  // g10
    o[12]=o[13]=cth*ca; o[14]=o[15]=cth*sa;   // g11
  }
  if (t >= 128 && t < 128 + NQ) {
    int q = t - 128;
    float xv = x[b*NQ + q];
    float sv, cv; sincosf(0.5f*xv, &sv, &cv);
    cs[q] = make_float2(cv, sv);
  }
  __syncthreads();

  // Precomputed byte-address bases (verified R5; per-access index static).
  int baseA[8], baseB[8];
  #pragma unroll
  for (int m = 0; m < 8; ++m) {
    baseA[m] = (t << 7) + (((2*m) ^ (t & 14)) << 3);                 // phys14, A b128
    baseB[m] = ((t >> 4) << 11) + ((((t & 15) ^ (2*m))) << 3);       // + j*128
  }
  const int baseC = ((t >> 4) << 7) + ((((t & 15) ^ ((t >> 4) & 15))) << 3);  // + j*2048
  const int G = t ^ (t >> 1);
  int baseS[2];
  #pragma unroll
  for (int par = 0; par < 2; ++par) {
    const int k8 = par << 3;
    baseS[par] = ((((G >> 4) & 15) ^ k8) << 7)
               + ((((G & 15) ^ ((G >> 4) & 14) ^ k8)) << 3);
  }

  f2 v[16];

  // ---- Init: amp(label) = prod_w (bit? sin:cos) * (-i)^popcount(label).
  // Pass-A ownership: label = t*16+j.
  {
    float2 csr[NQ];
    #pragma unroll
    for (int q = 0; q < NQ; ++q) csr[q] = cs[q];
    float rhi = 1.f;
    #pragma unroll
    for (int k = 0; k < 8; ++k)
      rhi *= ((t >> k) & 1) ? csr[7-k].y : csr[7-k].x;
    const int popt = __popc(t);
    #pragma unroll
    for (int j = 0; j < 16; ++j) {
      float r = rhi;
      #pragma unroll
      for (int m = 0; m < 4; ++m)
        r *= ((j >> m) & 1) ? csr[11-m].y : csr[11-m].x;
      const int pj = (popt + __popc(j)) & 3;    // static select per j
      if      (pj == 0) v[j] = (f2){ r, 0.f};
      else if (pj == 1) v[j] = (f2){0.f, -r};
      else if (pj == 2) v[j] = (f2){-r, 0.f};
      else              v[j] = (f2){0.f,  r};
    }
  }

  #define GATE(BIT, WQ)                                                     \
    { const f2* gp = (const f2*)(gmp + (((l*NQ) + (WQ)) << 4));             \
      apply_gate16<BIT>(v, gp[0], gp[1], gp[2], gp[3],                      \
                           gp[4], gp[5], gp[6], gp[7]); }

  #pragma unroll 1
  for (int l = 0; l < NL; ++l) {
    // ---- pass A: wires 11..8 (label bits 0..3)
    if (l > 0) {
      #pragma unroll
      for (int m = 0; m < 8; ++m) {
        float4 q4 = *(const float4*)(stb + baseA[m]);
        v[2*m]   = (f2){q4.x, q4.y};
        v[2*m+1] = (f2){q4.z, q4.w};
      }
    }
    GATE(0,11) GATE(1,10) GATE(2,9) GATE(3,8)
    #pragma unroll
    for (int m = 0; m < 8; ++m)
      *(float4*)(stb + baseA[m]) =
          make_float4(v[2*m].x, v[2*m].y, v[2*m+1].x, v[2*m+1].y);
    __syncthreads();

    // ---- pass B: wires 7..4 (label bits 4..7); load phys14, store phys15
    #pragma unroll
    for (int m = 0; m < 8; ++m) {
      v[2*m]   = *(const f2*)(stb + baseB[m] + (2*m)*128);
      v[2*m+1] = *(const f2*)(stb + baseB[m] + (2*m+1)*128);
    }
    GATE(0,7) GATE(1,6) GATE(2,5) GATE(3,4)
    #pragma unroll
    for (int m = 0; m < 8; ++m) {
      *(f2*)(stb + baseB[m] + (2*m)*128)         = v[2*m];
      *(f2*)(stb + (baseB[m] ^ 8) + (2*m+1)*128) = v[2*m+1];
    }
    __syncthreads();

    // ---- pass C: wires 3..0 (label bits 8..11); load phys15
    #pragma unroll
    for (int j = 0; j < 16; ++j)
      v[j] = *(const f2*)(stb + baseC + j*2048);
    GATE(0,3) GATE(1,2) GATE(2,1) GATE(3,0)
    if (l < NL-1) {
      // store with CNOT fold: slot = gray(label), layout phys14;
      // high nibble of gray(label) = gray4(j) (compile-time per j)
      #pragma unroll
      for (int j = 0; j < 16; ++j) {
        const int g4 = (j ^ (j >> 1)) & 15;
        *(f2*)(stb + baseS[j & 1] + (g4 << 11)) = v[j];
      }
      __syncthreads();
    }
  }

  // ---- Epilogue: labels s = t | j<<8; post-CNOT wire0 = j3, wire1 = j2^j3.
  float a0 = 0.f, a1 = 0.f;
  #pragma unroll
  for (int j = 0; j < 16; ++j) {
    float pr = v[j].x*v[j].x + v[j].y*v[j].y;
    a0 += ((j >> 3) & 1) ? -pr : pr;
    a1 += (((j >> 2) ^ (j >> 3)) & 1) ? -pr : pr;
  }
  #pragma unroll
  for (int off = 32; off >= 1; off >>= 1) {
    a0 += __shfl_down(a0, off);
    a1 += __shfl_down(a1, off);
  }
  __syncthreads();                 // all LDS reads done before st reuse
  if ((t & 63) == 0) { st[(t >> 6)*2] = a0; st[(t >> 6)*2 + 1] = a1; }
  __syncthreads();
  if (t == 0) {
    out[b*2 + 0] = st[0] + st[2] + st[4] + st[6];
    out[b*2 + 1] = st[1] + st[3] + st[5] + st[7];
  }
}

extern "C" void kernel_launch(void* const* d_in, const int* in_sizes, int n_in,
                              void* d_out, int out_size, void* d_ws, size_t ws_size,
                              hipStream_t stream) {
  const float* x = (const float*)d_in[0];      // (B, 12) f32
  const float* w = (const float*)d_in[1];      // (6, 12, 3) f32
  float* out = (float*)d_out;                  // (B, 2) f32
  int B = in_sizes[0] / NQ;
  qsim12_kernel<<<B, TPB, 0, stream>>>(x, w, out);
}

// Round 8
// 133.934 us; speedup vs baseline: 5.1767x; 1.1848x over previous
//
#include <hip/hip_runtime.h>
#include <math.h>

#define NQ 12
#define DIM 4096
#define NL 6
#define TPB 256

typedef float f2 __attribute__((ext_vector_type(2)));

// ---------------------------------------------------------------------------
// R8: RZ/RY factoring on top of R7's verified structure.
// Rot(phi,th,om) = RZ(om) RY(th) RZ(phi). Per layer: all 12 RZ(phi) merge
// into one diagonal D_phi (applied in pass A, post-load, pre-RY); all 12
// RZ(om) merge into D_om (applied in pass C, post-RY, pre-store). Diagonal
// phase splits by bit group: phase(s) = fGroup(j) + fThread(t); the 16
// group factors are shared (LDS tables zA/zC), the thread factor is one
// signed dot + sincos. RY pair updates have REAL coefficients -> 4 packed
// ops/pair (vs 8 for full Rot). D_om of the last layer is skipped: it
// cannot affect |amp|^2.
//
// Everything else (logical-basis state, CNOT fold = gray(label) at pass-C
// store, phys14/phys15 swizzles, address bases) is identical to R7
// (correctness-verified R5/R7).
// ---------------------------------------------------------------------------

__device__ __forceinline__ f2 pk_mul(f2 a, f2 b) {
  f2 d; asm("v_pk_mul_f32 %0, %1, %2" : "=v"(d) : "v"(a), "v"(b)); return d;
}
__device__ __forceinline__ f2 pk_fma(f2 a, f2 b, f2 c) {
  f2 d; asm("v_pk_fma_f32 %0, %1, %2, %3" : "=v"(d) : "v"(a), "v"(b), "v"(c)); return d;
}
// complex mul, both operands packed (re,im):
//   r1 = (a.re*c.re, a.re*c.im); d = (r1.lo - a.im*c.im, r1.hi + a.im*c.re)
__device__ __forceinline__ f2 cmulp(f2 a, f2 c) {
  f2 r1, d;
  asm("v_pk_mul_f32 %0, %1, %2 op_sel:[0,0] op_sel_hi:[0,1]"
      : "=v"(r1) : "v"(a), "v"(c));
  asm("v_pk_fma_f32 %0, %1, %2, %3 op_sel:[1,1,0] op_sel_hi:[1,0,1] neg_lo:[1,0,0]"
      : "=v"(d) : "v"(a), "v"(c), "v"(r1));
  return d;
}

// RY pair update: a' = c*a - s*b ; b' = s*a + c*b (real c,s duplicated)
template<int BIT>
__device__ __forceinline__ void apply_ry16(f2 v[16], f2 cc, f2 ss) {
  #pragma unroll
  for (int j = 0; j < 16; ++j) {
    if (j & (1 << BIT)) continue;
    const int k = j | (1 << BIT);
    f2 a = v[j], b = v[k];
    f2 t1 = pk_mul(a, cc);
    f2 t2 = pk_mul(a, ss);
    f2 na; asm("v_pk_fma_f32 %0, %1, %2, %3 neg_lo:[1,0,0] neg_hi:[1,0,0]"
               : "=v"(na) : "v"(b), "v"(ss), "v"(t1));
    f2 nb = pk_fma(b, cc, t2);
    v[j] = na; v[k] = nb;
  }
}

__global__ __launch_bounds__(TPB, 4)
void qsim12_kernel(const float* __restrict__ x, const float* __restrict__ w,
                   float* __restrict__ out) {
  __shared__ __align__(16) float st[2*DIM];   // 32 KB state (swizzled)
  __shared__ __align__(16) float4 ryt[NL*NQ]; // (c,c,s,s) per (l,wire)
  __shared__ f2 zA[NL*16];                    // e^{i*fA(j)} from phis, wires 11-8
  __shared__ f2 zC[NL*16];                    // e^{i*fC(j)} from oms,  wires 3-0
  __shared__ f2 phw[NL*NQ];                   // (phi, om) per (l,wire)
  __shared__ float2 cs[NQ];                   // cos/sin(x_q/2)

  const int t = threadIdx.x;
  const int b = blockIdx.x;
  char* stb = (char*)st;

  // ---- table setup (one barrier) ----
  if (t < 96) {                       // zA: l = t>>4, j = t&15 (bit m <-> wire 11-m)
    int l = t >> 4, j = t & 15;
    float ph = 0.f;
    #pragma unroll
    for (int m = 0; m < 4; ++m) {
      float phi = w[(l*NQ + (11 - m))*3 + 0];
      ph += ((j >> m) & 1) ? phi : -phi;
    }
    float sv, cv; sincosf(0.5f*ph, &sv, &cv);
    zA[t] = (f2){cv, sv};
  } else if (t < 192) {               // zC: bit m <-> wire 3-m
    int g = t - 96, l = g >> 4, j = g & 15;
    float ph = 0.f;
    #pragma unroll
    for (int m = 0; m < 4; ++m) {
      float om = w[(l*NQ + (3 - m))*3 + 2];
      ph += ((j >> m) & 1) ? om : -om;
    }
    float sv, cv; sincosf(0.5f*ph, &sv, &cv);
    zC[g] = (f2){cv, sv};
  } else {                            // ry + phw, g in [0,64)
    int g = t - 192;
    float th = w[g*3 + 1];
    float sv, cv; sincosf(0.5f*th, &sv, &cv);
    ryt[g] = make_float4(cv, cv, sv, sv);
    phw[g] = (f2){w[g*3 + 0], w[g*3 + 2]};
  }
  if (t < 8) {                        // remaining ry g = 64..71
    int g = 64 + t;
    float th = w[g*3 + 1];
    float sv, cv; sincosf(0.5f*th, &sv, &cv);
    ryt[g] = make_float4(cv, cv, sv, sv);
    phw[g] = (f2){w[g*3 + 0], w[g*3 + 2]};
  }
  if (t >= 244) {                     // cs, q = t-244
    int q = t - 244;
    float xv = x[b*NQ + q];
    float sv, cv; sincosf(0.5f*xv, &sv, &cv);
    cs[q] = make_float2(cv, sv);
  }
  __syncthreads();

  // Precomputed byte-address bases (verified R5/R7).
  int baseA[8], baseB[8];
  #pragma unroll
  for (int m = 0; m < 8; ++m) {
    baseA[m] = (t << 7) + (((2*m) ^ (t & 14)) << 3);                 // phys14, A b128
    baseB[m] = ((t >> 4) << 11) + ((((t & 15) ^ (2*m))) << 3);       // + j*128
  }
  const int baseC = ((t >> 4) << 7) + ((((t & 15) ^ ((t >> 4) & 15))) << 3);  // + j*2048
  const int G = t ^ (t >> 1);
  int baseS[2];
  #pragma unroll
  for (int par = 0; par < 2; ++par) {
    const int k8 = par << 3;
    baseS[par] = ((((G >> 4) & 15) ^ k8) << 7)
               + ((((G & 15) ^ ((G >> 4) & 14) ^ k8)) << 3);
  }
  // per-thread diagonal signs (0.5 factor folded in)
  float sg[8];
  #pragma unroll
  for (int k = 0; k < 8; ++k) sg[k] = ((t >> k) & 1) ? 0.5f : -0.5f;

  f2 v[16];

  // ---- Init: amp(label) = prod_w (bit? sin:cos) * (-i)^popcount(label).
  {
    float2 csr[NQ];
    #pragma unroll
    for (int q = 0; q < NQ; ++q) csr[q] = cs[q];
    float rhi = 1.f;
    #pragma unroll
    for (int k = 0; k < 8; ++k)
      rhi *= ((t >> k) & 1) ? csr[7-k].y : csr[7-k].x;
    const int popt = __popc(t);
    #pragma unroll
    for (int j = 0; j < 16; ++j) {
      float r = rhi;
      #pragma unroll
      for (int m = 0; m < 4; ++m)
        r *= ((j >> m) & 1) ? csr[11-m].y : csr[11-m].x;
      const int pj = (popt + __popc(j)) & 3;
      if      (pj == 0) v[j] = (f2){ r, 0.f};
      else if (pj == 1) v[j] = (f2){0.f, -r};
      else if (pj == 2) v[j] = (f2){-r, 0.f};
      else              v[j] = (f2){0.f,  r};
    }
  }

  #define RY(BIT, WQ)                                               \
    { float4 r = ryt[l*NQ + (WQ)];                                  \
      apply_ry16<BIT>(v, (f2){r.x, r.y}, (f2){r.z, r.w}); }

  #pragma unroll 1
  for (int l = 0; l < NL; ++l) {
    // per-thread diagonal phases: wA from phis (wires 7-0 <-> t bits 0..7
    // shifted: label bit 4+k = t_k <-> wire 7-k), wC from oms (label bit k =
    // t_k <-> wire 11-k)
    float fa = 0.f, fc = 0.f;
    #pragma unroll
    for (int k = 0; k < 8; ++k) {
      fa += sg[k] * phw[l*NQ + 7 - k].x;
      fc += sg[k] * phw[l*NQ + 11 - k].y;
    }
    f2 wA, wC;
    { float sv, cv; sincosf(fa, &sv, &cv); wA = (f2){cv, sv};
      sincosf(fc, &sv, &cv); wC = (f2){cv, sv}; }

    // ---- pass A: wires 11..8 (label bits 0..3)
    if (l > 0) {
      #pragma unroll
      for (int m = 0; m < 8; ++m) {
        float4 q4 = *(const float4*)(stb + baseA[m]);
        v[2*m]   = (f2){q4.x, q4.y};
        v[2*m+1] = (f2){q4.z, q4.w};
      }
    }
    #pragma unroll
    for (int j = 0; j < 16; ++j) {       // D_phi
      f2 z = zA[l*16 + j];
      v[j] = cmulp(cmulp(v[j], z), wA);
    }
    RY(0,11) RY(1,10) RY(2,9) RY(3,8)
    #pragma unroll
    for (int m = 0; m < 8; ++m)
      *(float4*)(stb + baseA[m]) =
          make_float4(v[2*m].x, v[2*m].y, v[2*m+1].x, v[2*m+1].y);
    __syncthreads();

    // ---- pass B: wires 7..4 (label bits 4..7); load phys14, store phys15
    #pragma unroll
    for (int m = 0; m < 8; ++m) {
      v[2*m]   = *(const f2*)(stb + baseB[m] + (2*m)*128);
      v[2*m+1] = *(const f2*)(stb + baseB[m] + (2*m+1)*128);
    }
    RY(0,7) RY(1,6) RY(2,5) RY(3,4)
    #pragma unroll
    for (int m = 0; m < 8; ++m) {
      *(f2*)(stb + baseB[m] + (2*m)*128)         = v[2*m];
      *(f2*)(stb + (baseB[m] ^ 8) + (2*m+1)*128) = v[2*m+1];
    }
    __syncthreads();

    // ---- pass C: wires 3..0 (label bits 8..11); load phys15
    #pragma unroll
    for (int j = 0; j < 16; ++j)
      v[j] = *(const f2*)(stb + baseC + j*2048);
    RY(0,3) RY(1,2) RY(2,1) RY(3,0)
    if (l < NL-1) {
      #pragma unroll
      for (int j = 0; j < 16; ++j) {     // D_om (skipped for last layer:
        f2 z = zC[l*16 + j];             //  cannot affect |amp|^2)
        v[j] = cmulp(cmulp(v[j], z), wC);
      }
      // store with CNOT fold: slot = gray(label), layout phys14;
      // high nibble of gray(label) = gray4(j)
      #pragma unroll
      for (int j = 0; j < 16; ++j) {
        const int g4 = (j ^ (j >> 1)) & 15;
        *(f2*)(stb + baseS[j & 1] + (g4 << 11)) = v[j];
      }
      __syncthreads();
    }
  }

  // ---- Epilogue: labels s = t | j<<8; post-CNOT wire0 = j3, wire1 = j2^j3.
  float a0 = 0.f, a1 = 0.f;
  #pragma unroll
  for (int j = 0; j < 16; ++j) {
    float pr = v[j].x*v[j].x + v[j].y*v[j].y;
    a0 += ((j >> 3) & 1) ? -pr : pr;
    a1 += (((j >> 2) ^ (j >> 3)) & 1) ? -pr : pr;
  }
  #pragma unroll
  for (int off = 32; off >= 1; off >>= 1) {
    a0 += __shfl_down(a0, off);
    a1 += __shfl_down(a1, off);
  }
  __syncthreads();                 // all LDS reads done before st reuse
  if ((t & 63) == 0) { st[(t >> 6)*2] = a0; st[(t >> 6)*2 + 1] = a1; }
  __syncthreads();
  if (t == 0) {
    out[b*2 + 0] = st[0] + st[2] + st[4] + st[6];
    out[b*2 + 1] = st[1] + st[3] + st[5] + st[7];
  }
}

extern "C" void kernel_launch(void* const* d_in, const int* in_sizes, int n_in,
                              void* d_out, int out_size, void* d_ws, size_t ws_size,
                              hipStream_t stream) {
  const float* x = (const float*)d_in[0];      // (B, 12) f32
  const float* w = (const float*)d_in[1];      // (6, 12, 3) f32
  float* out = (float*)d_out;                  // (B, 2) f32
  int B = in_sizes[0] / NQ;
  qsim12_kernel<<<B, TPB, 0, stream>>>(x, w, out);
}